// Round 1
// baseline (44.329 us; speedup 1.0000x reference)
//
#include <hip/hip_runtime.h>

#define EPSF 1e-7f
#define SCALEF (1.0f / 7.0f)

__device__ __forceinline__ float pair_iou(const float* b1, const float* b2) {
    // faithful to reference: width/height recomputed from corners, eps placement kept
    float b1x1 = b1[0] - b1[2] * 0.5f, b1x2 = b1[0] + b1[2] * 0.5f;
    float b1y1 = b1[1] - b1[3] * 0.5f, b1y2 = b1[1] + b1[3] * 0.5f;
    float b2x1 = b2[0] - b2[2] * 0.5f, b2x2 = b2[0] + b2[2] * 0.5f;
    float b2y1 = b2[1] - b2[3] * 0.5f, b2y2 = b2[1] + b2[3] * 0.5f;
    float iw = fmaxf(fminf(b1x2, b2x2) - fmaxf(b1x1, b2x1), 0.0f);
    float ih = fmaxf(fminf(b1y2, b2y2) - fmaxf(b1y1, b2y1), 0.0f);
    float inter = iw * ih + EPSF;
    float w1 = b1x2 - b1x1, h1 = b1y2 - b1y1 + EPSF;
    float w2 = b2x2 - b2x1, h2 = b2y2 - b2y1 + EPSF;
    float uni = w1 * h1 + w2 * h2 - inter + EPSF;
    return inter / uni;
}

__global__ __launch_bounds__(256) void yolo_loss_partial(
        const float* __restrict__ pre, const float* __restrict__ targ,
        float* __restrict__ partial, int n_cells) {
    int cell = blockIdx.x * 256 + threadIdx.x;
    float loss = 0.0f;
    if (cell < n_cells) {
        float p[30], t[30];
        const float2* p2 = reinterpret_cast<const float2*>(pre + (size_t)cell * 30);
        const float2* t2 = reinterpret_cast<const float2*>(targ + (size_t)cell * 30);
#pragma unroll
        for (int i = 0; i < 15; ++i) { float2 v = p2[i]; p[2 * i] = v.x; p[2 * i + 1] = v.y; }
#pragma unroll
        for (int i = 0; i < 15; ++i) { float2 v = t2[i]; t[2 * i] = v.x; t[2 * i + 1] = v.y; }

        bool cell_obj   = t[4] > 0.0f;
        bool cell_noobj = t[4] == 0.0f;

        float iou0 = pair_iou(p + 0, t + 0);
        float iou1 = pair_iou(p + 5, t + 5);
        // jnp.argmax/argmin first-occurrence semantics on 2 elements:
        int resp    = (iou1 > iou0) ? 1 : 0;
        int nonresp = (iou1 < iou0) ? 1 : 0;

        // fxy from the NON-responsible box's target xy (static indexing only)
        float xnr = nonresp ? t[5] : t[0];
        float ynr = nonresp ? t[6] : t[1];
        float fx = (xnr - (ceilf(xnr / SCALEF) - 1.0f) * SCALEF) / SCALEF;
        float fy = (ynr - (ceilf(ynr / SCALEF) - 1.0f) * SCALEF) / SCALEF;

        float lxy = 0.0f, lwh = 0.0f, lconf = 0.0f, lnoconf = 0.0f, lclass = 0.0f;
#pragma unroll
        for (int i = 0; i < 2; ++i) {
            const float* pb = p + i * 5;
            const float* tb = t + i * 5;
            bool is_resp    = (i == resp);
            bool is_nonresp = (i == nonresp);
            float new_conf = is_nonresp ? 0.0f : tb[4];
            if (cell_obj) {
                if (is_resp) {
                    float dx = pb[0] - fx, dy = pb[1] - fy;
                    lxy += dx * dx + dy * dy;
                    float dw = sqrtf(pb[2] + EPSF) - sqrtf(tb[2] + EPSF);
                    float dh = sqrtf(pb[3] + EPSF) - sqrtf(tb[3] + EPSF);
                    lwh += dw * dw + dh * dh;
                    float dc = pb[4] - new_conf;
                    lconf += dc * dc;
                } else {
                    float dc = pb[4] - new_conf;
                    lnoconf += dc * dc;
                }
            }
            if (cell_noobj) {
                float dc = pb[4] - tb[4];
                lnoconf += dc * dc;
            }
        }
        if (cell_obj) {
#pragma unroll
            for (int k = 10; k < 30; ++k) { float d = p[k] - t[k]; lclass += d * d; }
        }
        loss = 5.0f * (lxy + lwh) + lclass + lconf + 0.5f * lnoconf;
    }

    // wave64 shuffle reduce, then cross-wave via LDS
#pragma unroll
    for (int off = 32; off > 0; off >>= 1) loss += __shfl_down(loss, off, 64);
    __shared__ float ssum[4];
    int lane = threadIdx.x & 63, wid = threadIdx.x >> 6;
    if (lane == 0) ssum[wid] = loss;
    __syncthreads();
    if (threadIdx.x == 0) partial[blockIdx.x] = ssum[0] + ssum[1] + ssum[2] + ssum[3];
}

__global__ __launch_bounds__(256) void yolo_loss_final(
        const float* __restrict__ partial, int n, float invB, float* __restrict__ out) {
    float v = 0.0f;
    for (int i = threadIdx.x; i < n; i += 256) v += partial[i];
#pragma unroll
    for (int off = 32; off > 0; off >>= 1) v += __shfl_down(v, off, 64);
    __shared__ float ssum[4];
    int lane = threadIdx.x & 63, wid = threadIdx.x >> 6;
    if (lane == 0) ssum[wid] = v;
    __syncthreads();
    if (threadIdx.x == 0) out[0] = (ssum[0] + ssum[1] + ssum[2] + ssum[3]) * invB;
}

extern "C" void kernel_launch(void* const* d_in, const int* in_sizes, int n_in,
                              void* d_out, int out_size, void* d_ws, size_t ws_size,
                              hipStream_t stream) {
    const float* pre  = (const float*)d_in[0];
    const float* targ = (const float*)d_in[1];
    float* out = (float*)d_out;
    float* partial = (float*)d_ws;

    int B = in_sizes[0] / 1470;       // 16384
    int n_cells = B * 49;             // 802816
    int nblocks = (n_cells + 255) / 256;  // 3136

    yolo_loss_partial<<<nblocks, 256, 0, stream>>>(pre, targ, partial, n_cells);
    yolo_loss_final<<<1, 256, 0, stream>>>(partial, nblocks, 1.0f / (float)B, out);
}

// Round 2
// 37.631 us; speedup vs baseline: 1.1780x; 1.1780x over previous
//
#include <hip/hip_runtime.h>

#define EPSF 1e-7f
#define SCALEF (1.0f / 7.0f)

__device__ __forceinline__ float pair_iou(const float* b1, const float* b2) {
    float b1x1 = b1[0] - b1[2] * 0.5f, b1x2 = b1[0] + b1[2] * 0.5f;
    float b1y1 = b1[1] - b1[3] * 0.5f, b1y2 = b1[1] + b1[3] * 0.5f;
    float b2x1 = b2[0] - b2[2] * 0.5f, b2x2 = b2[0] + b2[2] * 0.5f;
    float b2y1 = b2[1] - b2[3] * 0.5f, b2y2 = b2[1] + b2[3] * 0.5f;
    float iw = fmaxf(fminf(b1x2, b2x2) - fmaxf(b1x1, b2x1), 0.0f);
    float ih = fmaxf(fminf(b1y2, b2y2) - fmaxf(b1y1, b2y1), 0.0f);
    float inter = iw * ih + EPSF;
    float w1 = b1x2 - b1x1, h1 = b1y2 - b1y1 + EPSF;
    float w2 = b2x2 - b2x1, h2 = b2y2 - b2y1 + EPSF;
    float uni = w1 * h1 + w2 * h2 - inter + EPSF;
    return inter / uni;
}

// Block = 256 threads, handles 256 cells in 2 chunks of 128.
// Per chunk: coalesced float4 staging of 128 cells x 30 floats x 2 arrays
// into linear LDS (30720 B -> 5 blocks/CU), then wave-uniform split:
// waves 0-1 compute box/conf terms (floats 0..9), waves 2-3 class (10..29).
__global__ __launch_bounds__(256) void yolo_loss_partial(
        const float* __restrict__ pre, const float* __restrict__ targ,
        float* __restrict__ partial) {
    __shared__ float4 s4[1920];                      // [0,960) = pre, [960,1920) = targ
    float* sp = reinterpret_cast<float*>(s4);        // 128*30 floats
    float* st = reinterpret_cast<float*>(s4 + 960);
    const int tid = threadIdx.x;
    float acc = 0.0f;

#pragma unroll
    for (int chunk = 0; chunk < 2; ++chunk) {
        const size_t base = ((size_t)blockIdx.x * 256 + chunk * 128) * 30;
        const float4* gp = reinterpret_cast<const float4*>(pre + base);   // 16B-aligned: base*4 % 16 == 0
        const float4* gt = reinterpret_cast<const float4*>(targ + base);
        float4* sp4 = s4;
        float4* st4 = s4 + 960;
#pragma unroll
        for (int k = 0; k < 3; ++k) {                // 960 float4 per array, 256 threads
            int idx = tid + 256 * k;
            sp4[idx] = gp[idx];
            st4[idx] = gt[idx];
        }
        {
            int idx = tid + 768;
            if (idx < 960) { sp4[idx] = gp[idx]; st4[idx] = gt[idx]; }
        }
        __syncthreads();

        const int half = tid >> 7;                   // wave-uniform: waves 0-1 box, 2-3 class
        const int c = tid & 127;                     // cell within chunk
        const float* cp = sp + c * 30;
        const float* ct = st + c * 30;
        float loss = 0.0f;
        if (half == 0) {
            float p[10], t[10];
            const float2* cp2 = reinterpret_cast<const float2*>(cp);
            const float2* ct2 = reinterpret_cast<const float2*>(ct);
#pragma unroll
            for (int i = 0; i < 5; ++i) {
                float2 a = cp2[i]; p[2 * i] = a.x; p[2 * i + 1] = a.y;
                float2 b = ct2[i]; t[2 * i] = b.x; t[2 * i + 1] = b.y;
            }
            bool cell_obj   = t[4] > 0.0f;
            bool cell_noobj = t[4] == 0.0f;
            float iou0 = pair_iou(p + 0, t + 0);
            float iou1 = pair_iou(p + 5, t + 5);
            int resp    = (iou1 > iou0) ? 1 : 0;     // jnp.argmax first-index semantics
            int nonresp = (iou1 < iou0) ? 1 : 0;
            float xnr = nonresp ? t[5] : t[0];
            float ynr = nonresp ? t[6] : t[1];
            float fx = (xnr - (ceilf(xnr / SCALEF) - 1.0f) * SCALEF) / SCALEF;
            float fy = (ynr - (ceilf(ynr / SCALEF) - 1.0f) * SCALEF) / SCALEF;
            float lxy = 0.0f, lwh = 0.0f, lconf = 0.0f, lnoconf = 0.0f;
#pragma unroll
            for (int i = 0; i < 2; ++i) {
                const float* pb = p + i * 5;
                const float* tb = t + i * 5;
                bool is_resp    = (i == resp);
                bool is_nonresp = (i == nonresp);
                float new_conf = is_nonresp ? 0.0f : tb[4];
                if (cell_obj) {
                    if (is_resp) {
                        float dx = pb[0] - fx, dy = pb[1] - fy;
                        lxy += dx * dx + dy * dy;
                        float dw = sqrtf(pb[2] + EPSF) - sqrtf(tb[2] + EPSF);
                        float dh = sqrtf(pb[3] + EPSF) - sqrtf(tb[3] + EPSF);
                        lwh += dw * dw + dh * dh;
                        float dc = pb[4] - new_conf;
                        lconf += dc * dc;
                    } else {
                        float dc = pb[4] - new_conf;
                        lnoconf += dc * dc;
                    }
                }
                if (cell_noobj) {
                    float dc = pb[4] - tb[4];
                    lnoconf += dc * dc;
                }
            }
            loss = 5.0f * (lxy + lwh) + lconf + 0.5f * lnoconf;
        } else {
            float tobj = ct[4];
            if (tobj > 0.0f) {
                float s = 0.0f;
                const float2* cp2 = reinterpret_cast<const float2*>(cp + 10);
                const float2* ct2 = reinterpret_cast<const float2*>(ct + 10);
#pragma unroll
                for (int i = 0; i < 10; ++i) {
                    float2 a = cp2[i], b = ct2[i];
                    float d0 = a.x - b.x, d1 = a.y - b.y;
                    s += d0 * d0 + d1 * d1;
                }
                loss = s;
            }
        }
        acc += loss;
        __syncthreads();                             // protect LDS reuse by next chunk
    }

    // wave64 shuffle reduce, then cross-wave via LDS
#pragma unroll
    for (int off = 32; off > 0; off >>= 1) acc += __shfl_down(acc, off, 64);
    __shared__ float ssum[4];
    int lane = tid & 63, wid = tid >> 6;
    if (lane == 0) ssum[wid] = acc;
    __syncthreads();
    if (tid == 0) partial[blockIdx.x] = ssum[0] + ssum[1] + ssum[2] + ssum[3];
}

__global__ __launch_bounds__(256) void yolo_loss_final(
        const float* __restrict__ partial, int n, float invB, float* __restrict__ out) {
    float v = 0.0f;
    for (int i = threadIdx.x; i < n; i += 256) v += partial[i];
#pragma unroll
    for (int off = 32; off > 0; off >>= 1) v += __shfl_down(v, off, 64);
    __shared__ float ssum[4];
    int lane = threadIdx.x & 63, wid = threadIdx.x >> 6;
    if (lane == 0) ssum[wid] = v;
    __syncthreads();
    if (threadIdx.x == 0) out[0] = (ssum[0] + ssum[1] + ssum[2] + ssum[3]) * invB;
}

extern "C" void kernel_launch(void* const* d_in, const int* in_sizes, int n_in,
                              void* d_out, int out_size, void* d_ws, size_t ws_size,
                              hipStream_t stream) {
    const float* pre  = (const float*)d_in[0];
    const float* targ = (const float*)d_in[1];
    float* out = (float*)d_out;
    float* partial = (float*)d_ws;

    int B = in_sizes[0] / 1470;            // 16384
    int n_cells = B * 49;                  // 802816 = 3136 * 256 exactly
    int nblocks = n_cells / 256;           // 3136

    yolo_loss_partial<<<nblocks, 256, 0, stream>>>(pre, targ, partial);
    yolo_loss_final<<<1, 256, 0, stream>>>(partial, nblocks, 1.0f / (float)B, out);
}